// Round 2
// baseline (923.858 us; speedup 1.0000x reference)
//
#include <hip/hip_runtime.h>
#include <hip/hip_bf16.h>

#define NN 50000
#define NE 800000
#define NT_E 12500   // 800000 / 64

typedef __attribute__((ext_vector_type(8))) short bf16x8;   // 8 bf16 (4 VGPRs)
typedef __attribute__((ext_vector_type(4))) float f32x4;
typedef __attribute__((ext_vector_type(8))) unsigned short u16x8;

__device__ __forceinline__ unsigned short f2bf(float f) {
    union { float f; unsigned u; } v; v.f = f;
    unsigned r = v.u + 0x7FFFu + ((v.u >> 16) & 1u);   // RNE
    return (unsigned short)(r >> 16);
}
__device__ __forceinline__ float bf2f(unsigned short h) {
    union { unsigned u; float f; } v; v.u = ((unsigned)h) << 16;
    return v.f;
}
__device__ __forceinline__ f32x4 mfma16(bf16x8 a, bf16x8 b, f32x4 c) {
    return __builtin_amdgcn_mfma_f32_16x16x32_bf16(a, b, c, 0, 0, 0);
}

// ---- weight fragment loader: B[k][n] = W[n][k]; lane holds W[nt*16+(l&15)][kk*32+8*(l>>4)..+7]
__device__ __forceinline__ void load_wfrags(const unsigned short* __restrict__ Wb,
                                            int wv, int lane, bf16x8 (&wf)[4][2]) {
#pragma unroll
    for (int kk = 0; kk < 4; ++kk)
#pragma unroll
        for (int j = 0; j < 2; ++j) {
            int row = 32 * wv + 16 * j + (lane & 15);
            int col = 32 * kk + 8 * (lane >> 4);
            wf[kk][j] = *(const bf16x8*)(Wb + row * 128 + col);
        }
}

__device__ __forceinline__ void zero_acc(f32x4 (&acc)[4][2]) {
#pragma unroll
    for (int mt = 0; mt < 4; ++mt)
#pragma unroll
        for (int j = 0; j < 2; ++j) {
            f32x4 z = {0.f, 0.f, 0.f, 0.f};
            acc[mt][j] = z;
        }
}

// ---- GEMM: out[64][cols of this wave] += X[64][128] * W^T ; X padded [64][136]
__device__ __forceinline__ void gemm64(const unsigned short* __restrict__ X,
                                       const bf16x8 (&wf)[4][2], f32x4 (&acc)[4][2], int lane) {
#pragma unroll
    for (int kk = 0; kk < 4; ++kk) {
        bf16x8 a[4];
#pragma unroll
        for (int mt = 0; mt < 4; ++mt) {
            int row = mt * 16 + (lane & 15);
            a[mt] = *(const bf16x8*)(X + row * 136 + kk * 32 + 8 * (lane >> 4));
        }
#pragma unroll
        for (int mt = 0; mt < 4; ++mt) {
            acc[mt][0] = mfma16(a[mt], wf[kk][0], acc[mt][0]);
            acc[mt][1] = mfma16(a[mt], wf[kk][1], acc[mt][1]);
        }
    }
}

// ---- epilogue: relu(acc+bias) -> bf16 LDS tile
__device__ __forceinline__ void epi_lds(unsigned short* __restrict__ Xo,
                                        const f32x4 (&acc)[4][2],
                                        float bb0, float bb1, int c0, int rbase) {
#pragma unroll
    for (int mt = 0; mt < 4; ++mt)
#pragma unroll
        for (int r = 0; r < 4; ++r) {
            int row = mt * 16 + rbase + r;
            Xo[row * 136 + c0]      = f2bf(fmaxf(acc[mt][0][r] + bb0, 0.f));
            Xo[row * 136 + c0 + 16] = f2bf(fmaxf(acc[mt][1][r] + bb1, 0.f));
        }
}

// ---- fp32 row -> bf16x8 LDS stage helper
__device__ __forceinline__ void stage_f32row(unsigned short* __restrict__ Xrow,
                                             const f32x4* __restrict__ p) {
#pragma unroll
    for (int i = 0; i < 4; ++i) {
        f32x4 lo = p[2 * i], hi = p[2 * i + 1];
        unsigned short tmp[8];
#pragma unroll
        for (int j = 0; j < 4; ++j) { tmp[j] = f2bf(lo[j]); tmp[4 + j] = f2bf(hi[j]); }
        *(u16x8*)(Xrow + i * 8) = *(u16x8*)tmp;
    }
}

// ================= kernel 1: convert 9 DxD fp32 weights to bf16 =================
__global__ void k_wconv(const float* w0, const float* w1, const float* w2,
                        const float* w3, const float* w4, const float* w5,
                        const float* w6, const float* w7, const float* w8,
                        unsigned short* out) {
    const float* ws[9] = {w0, w1, w2, w3, w4, w5, w6, w7, w8};
    int m = blockIdx.x >> 2;
    int part = blockIdx.x & 3;
    const float* w = ws[m] + part * 4096 + threadIdx.x * 16;
    unsigned short* o = out + m * 16384 + part * 4096 + threadIdx.x * 16;
    float f[16];
#pragma unroll
    for (int i = 0; i < 4; ++i) *(f32x4*)(f + 4 * i) = ((const f32x4*)w)[i];
    unsigned short tmp[16];
#pragma unroll
    for (int i = 0; i < 16; ++i) tmp[i] = f2bf(f[i]);
    ((u16x8*)o)[0] = *(u16x8*)tmp;
    ((u16x8*)o)[1] = *(u16x8*)(tmp + 8);
}

// ================= sort kernels: hist -> in-place exclusive scan -> perm =======
__global__ void k_hist(const int* __restrict__ dst, int* __restrict__ cnt) {
    int i = blockIdx.x * 256 + threadIdx.x;
    int stride = gridDim.x * 256;
    for (; i < NE; i += stride) atomicAdd(&cnt[dst[i]], 1);
}

__global__ void k_scan(int* __restrict__ c) {   // 1 block, 1024 threads, in place
    __shared__ int part[1024];
    int tid = threadIdx.x;
    const int CH = 49;                          // 1024*49 >= NN
    int base = tid * CH;
    int s = 0;
    for (int i = 0; i < CH; ++i) { int idx = base + i; if (idx < NN) s += c[idx]; }
    part[tid] = s;
    __syncthreads();
    for (int off = 1; off < 1024; off <<= 1) {
        int v = (tid >= off) ? part[tid - off] : 0;
        __syncthreads();
        part[tid] += v;
        __syncthreads();
    }
    int excl = (tid == 0) ? 0 : part[tid - 1];
    for (int i = 0; i < CH; ++i) {
        int idx = base + i;
        if (idx < NN) { int cc = c[idx]; c[idx] = excl; excl += cc; }
    }
}

__global__ void k_perm(const int* __restrict__ dst, int* __restrict__ cursor,
                       int* __restrict__ perm) {
    int i = blockIdx.x * 256 + threadIdx.x;
    int stride = gridDim.x * 256;
    for (; i < NE; i += stride) {
        int p = atomicAdd(&cursor[dst[i]], 1);
        perm[p] = i;
    }
}

// ================= kernel 2: node pre: A_src, A_dst =================
__global__ __launch_bounds__(256, 3)
void k_nodepre(const float* __restrict__ h,
               const unsigned short* __restrict__ Wb,
               const float* __restrict__ bsrc, const float* __restrict__ bdst,
               unsigned short* __restrict__ Asrc, unsigned short* __restrict__ Adst) {
    __shared__ unsigned short X[64 * 136];
    int tid = threadIdx.x, lane = tid & 63, wv = tid >> 6;
    int n0 = blockIdx.x * 64;
    {
        int row = tid >> 2, q = tid & 3;
        int n = n0 + row;
        if (n < NN) {
            stage_f32row(X + row * 136 + q * 32,
                         (const f32x4*)(h + (size_t)n * 128 + q * 32));
        } else {
            u16x8 z = {0, 0, 0, 0, 0, 0, 0, 0};
#pragma unroll
            for (int i = 0; i < 4; ++i) *(u16x8*)(X + row * 136 + q * 32 + i * 8) = z;
        }
    }
    __syncthreads();

    bf16x8 wfS[4][2], wfD[4][2];
    load_wfrags(Wb, wv, lane, wfS);            // Wsrc
    load_wfrags(Wb + 16384, wv, lane, wfD);    // Wdst
    f32x4 accS[4][2], accD[4][2];
    zero_acc(accS); zero_acc(accD);
    gemm64(X, wfS, accS, lane);
    gemm64(X, wfD, accD, lane);

    int c0 = 32 * wv + (lane & 15);
    float bs0 = bsrc[c0], bs1 = bsrc[c0 + 16];
    float bd0 = bdst[c0], bd1 = bdst[c0 + 16];
    int rbase = (lane >> 4) * 4;
#pragma unroll
    for (int mt = 0; mt < 4; ++mt)
#pragma unroll
        for (int r = 0; r < 4; ++r) {
            int n = n0 + mt * 16 + rbase + r;
            if (n < NN) {
                size_t o = (size_t)n * 128;
                Asrc[o + c0]      = f2bf(accS[mt][0][r] + bs0);
                Asrc[o + c0 + 16] = f2bf(accS[mt][1][r] + bs1);
                Adst[o + c0]      = f2bf(accD[mt][0][r] + bd0);
                Adst[o + c0 + 16] = f2bf(accD[mt][1][r] + bd1);
            }
        }
}

// ================= kernel 3: edge MLP (sorted order) + segmented scatter =======
__global__ __launch_bounds__(256, 3)
void k_edge(const float* __restrict__ ef,
            const float* __restrict__ nf,
            const int* __restrict__ src, const int* __restrict__ dst,
            const int* __restrict__ perm,
            const unsigned short* __restrict__ Asrc,
            const unsigned short* __restrict__ Adst,
            const unsigned short* __restrict__ Wb,
            const float* __restrict__ b1, const float* __restrict__ b2,
            const float* __restrict__ b3,
            float* __restrict__ agg) {
    __shared__ __align__(16) char sh[52992];
    unsigned short* X0 = (unsigned short*)sh;             // [64][136] bf16
    unsigned short* X1 = (unsigned short*)(sh + 17408);   // [64][136] bf16
    float*          Mf = (float*)sh;                      // [64][128] f32, overlays X0+X1
    unsigned short* Hs = (unsigned short*)(sh + 34816);   // [64][136] bf16
    int* soff = (int*)(sh + 52224);
    int* didx = (int*)(sh + 52480);
    int* eidx = (int*)(sh + 52736);

    int tid = threadIdx.x, lane = tid & 63, wv = tid >> 6;

    bf16x8 wf1[4][2], wf2[4][2], wf3[4][2];
    load_wfrags(Wb + 2 * 16384, wv, lane, wf1);   // Wphi1
    load_wfrags(Wb + 3 * 16384, wv, lane, wf2);   // Wphi2
    load_wfrags(Wb + 4 * 16384, wv, lane, wf3);   // Wphi3

    int c0 = 32 * wv + (lane & 15);
    float b1_0 = b1[c0], b1_1 = b1[c0 + 16];
    float b2_0 = b2[c0], b2_1 = b2[c0 + 16];
    float b3_0 = b3[c0], b3_1 = b3[c0 + 16];
    int rbase = (lane >> 4) * 4;
    int srow = tid >> 2, q = tid & 3;

    // chunked contiguous tile ownership (sorted-by-dst => small dst window/block)
    int b = blockIdx.x, nb = gridDim.x;
    int qt = NT_E / nb, rt = NT_E % nb;
    int t0 = (b < rt) ? b * (qt + 1) : rt * (qt + 1) + (b - rt) * qt;
    int t1 = t0 + ((b < rt) ? qt + 1 : qt);

    for (int t = t0; t < t1; ++t) {
        int e0 = t * 64;
        __syncthreads();                       // prev tile's Mf/didx reads done
        if (tid < 64) {
            int e = perm[e0 + tid];
            eidx[tid] = e;
            soff[tid] = src[e] * 128;
            didx[tid] = dst[e];
        }
        __syncthreads();
        {   // stage X0 = relu(e + asrc + adst) bf16, Hs = bf16(node_feat[src])
            int e = eidx[srow];
            int so = soff[srow];
            int dofs = didx[srow] * 128;
            const f32x4* ep = (const f32x4*)(ef + (size_t)e * 128 + q * 32);
            const f32x4* hp = (const f32x4*)(nf + (size_t)so + q * 32);
            const u16x8* ap = (const u16x8*)(Asrc + so + q * 32);
            const u16x8* dp = (const u16x8*)(Adst + dofs + q * 32);
#pragma unroll
            for (int i = 0; i < 4; ++i) {
                u16x8 a8 = ap[i], d8 = dp[i];
                f32x4 e_lo = ep[2 * i], e_hi = ep[2 * i + 1];
                f32x4 h_lo = hp[2 * i], h_hi = hp[2 * i + 1];
                unsigned short o[8], hb[8];
#pragma unroll
                for (int j = 0; j < 8; ++j) {
                    float evv = (j < 4) ? e_lo[j] : e_hi[j - 4];
                    float hv  = (j < 4) ? h_lo[j] : h_hi[j - 4];
                    float v = evv + bf2f((unsigned short)a8[j]) + bf2f((unsigned short)d8[j]);
                    o[j] = f2bf(fmaxf(v, 0.f));
                    hb[j] = f2bf(hv);
                }
                *(u16x8*)(X0 + srow * 136 + q * 32 + i * 8) = *(u16x8*)o;
                *(u16x8*)(Hs + srow * 136 + q * 32 + i * 8) = *(u16x8*)hb;
            }
        }
        __syncthreads();
        f32x4 acc[4][2];
        zero_acc(acc);
        gemm64(X0, wf1, acc, lane);
        __syncthreads();                       // all X0 reads done
        epi_lds(X1, acc, b1_0, b1_1, c0, rbase);
        __syncthreads();                       // X1 writes done
        zero_acc(acc);
        gemm64(X1, wf2, acc, lane);
        epi_lds(X0, acc, b2_0, b2_1, c0, rbase);
        __syncthreads();                       // X0 writes done
        zero_acc(acc);
        gemm64(X0, wf3, acc, lane);
        __syncthreads();                       // X0 (Mf region) reads done
        // m = h_src * (e_emb + b3) -> Mf (fp32)
#pragma unroll
        for (int mt = 0; mt < 4; ++mt)
#pragma unroll
            for (int r = 0; r < 4; ++r) {
                int row = mt * 16 + rbase + r;
                float h0 = bf2f(Hs[row * 136 + c0]);
                float h1 = bf2f(Hs[row * 136 + c0 + 16]);
                Mf[row * 128 + c0]      = (acc[mt][0][r] + b3_0) * h0;
                Mf[row * 128 + c0 + 16] = (acc[mt][1][r] + b3_1) * h1;
            }
        __syncthreads();
        // segmented column reduction over sorted dst; ~1 atomic per (segment,col)
        {
            int col = tid & 127;
            int r0 = (tid >> 7) * 32;
            float s = 0.f;
            int cur = didx[r0];
            for (int r = r0; r < r0 + 32; ++r) {
                int d2 = didx[r];
                if (d2 != cur) {
                    atomicAdd(agg + (size_t)cur * 128 + col, s);
                    s = 0.f; cur = d2;
                }
                s += Mf[r * 128 + col];
            }
            atomicAdd(agg + (size_t)cur * 128 + col, s);
        }
    }
}

// ================= kernel 4: node output =================
__global__ __launch_bounds__(256, 3)
void k_nodeout(const float* __restrict__ h,
               const float* __restrict__ agg,
               const unsigned short* __restrict__ Wb,
               const float* __restrict__ bpd, const float* __restrict__ bpu,
               const float* __restrict__ bt1, const float* __restrict__ bt2,
               float* __restrict__ out) {
    __shared__ unsigned short Xh[64 * 136];
    __shared__ unsigned short Xa[64 * 136];
    int tid = threadIdx.x, lane = tid & 63, wv = tid >> 6;
    int n0 = blockIdx.x * 64;
    {
        int row = tid >> 2, q = tid & 3;
        int n = n0 + row;
        if (n < NN) {
            stage_f32row(Xh + row * 136 + q * 32,
                         (const f32x4*)(h + (size_t)n * 128 + q * 32));
            stage_f32row(Xa + row * 136 + q * 32,
                         (const f32x4*)(agg + (size_t)n * 128 + q * 32));
        } else {
            u16x8 z = {0, 0, 0, 0, 0, 0, 0, 0};
#pragma unroll
            for (int i = 0; i < 4; ++i) {
                *(u16x8*)(Xh + row * 136 + q * 32 + i * 8) = z;
                *(u16x8*)(Xa + row * 136 + q * 32 + i * 8) = z;
            }
        }
    }
    __syncthreads();
    bf16x8 wfa[4][2], wfb[4][2];
    load_wfrags(Wb + 5 * 16384, wv, lane, wfa);   // Wpd
    load_wfrags(Wb + 6 * 16384, wv, lane, wfb);   // Wpu
    int c0 = 32 * wv + (lane & 15);
    int rbase = (lane >> 4) * 4;
    f32x4 acc[4][2];
    zero_acc(acc);
    gemm64(Xh, wfa, acc, lane);
    gemm64(Xa, wfb, acc, lane);
    float bb0 = bpd[c0] + bpu[c0], bb1 = bpd[c0 + 16] + bpu[c0 + 16];
    __syncthreads();
    epi_lds(Xh, acc, bb0, bb1, c0, rbase);        // y1 = relu(...)
    __syncthreads();
    load_wfrags(Wb + 7 * 16384, wv, lane, wfa);   // Wth1
    zero_acc(acc);
    gemm64(Xh, wfa, acc, lane);
    float b10 = bt1[c0], b11 = bt1[c0 + 16];
    __syncthreads();
    epi_lds(Xa, acc, b10, b11, c0, rbase);        // y2 = relu(...)
    __syncthreads();
    load_wfrags(Wb + 8 * 16384, wv, lane, wfb);   // Wth2
    zero_acc(acc);
    gemm64(Xa, wfb, acc, lane);
    float b20 = bt2[c0], b21 = bt2[c0 + 16];
#pragma unroll
    for (int mt = 0; mt < 4; ++mt)
#pragma unroll
        for (int r = 0; r < 4; ++r) {
            int n = n0 + mt * 16 + rbase + r;
            if (n < NN) {
                out[(size_t)n * 128 + c0]      = acc[mt][0][r] + b20;
                out[(size_t)n * 128 + c0 + 16] = acc[mt][1][r] + b21;
            }
        }
}

extern "C" void kernel_launch(void* const* d_in, const int* in_sizes, int n_in,
                              void* d_out, int out_size, void* d_ws, size_t ws_size,
                              hipStream_t stream) {
    (void)in_sizes; (void)n_in; (void)out_size; (void)ws_size;
    const float* node_feat = (const float*)d_in[0];
    const float* edge_feat = (const float*)d_in[1];
    const int*   src  = (const int*)d_in[2];
    const int*   dst  = (const int*)d_in[3];
    const float* Wsrc = (const float*)d_in[4];  const float* bsrc = (const float*)d_in[5];
    const float* Wdst = (const float*)d_in[6];  const float* bdst = (const float*)d_in[7];
    const float* Wphi1 = (const float*)d_in[8]; const float* bphi1 = (const float*)d_in[9];
    const float* Wphi2 = (const float*)d_in[10];const float* bphi2 = (const float*)d_in[11];
    const float* Wphi3 = (const float*)d_in[12];const float* bphi3 = (const float*)d_in[13];
    const float* Wth1 = (const float*)d_in[14]; const float* bth1 = (const float*)d_in[15];
    const float* Wth2 = (const float*)d_in[16]; const float* bth2 = (const float*)d_in[17];
    const float* Wpd  = (const float*)d_in[18]; const float* bpd  = (const float*)d_in[19];
    const float* Wpu  = (const float*)d_in[20]; const float* bpu  = (const float*)d_in[21];

    // workspace layout (~54.9 MB)
    char* ws = (char*)d_ws;
    unsigned short* Wb   = (unsigned short*)ws;                    // 294,912 B
    unsigned short* Asrc = (unsigned short*)(ws + 294912);         // 12.8 MB
    unsigned short* Adst = (unsigned short*)(ws + 13094912);       // 12.8 MB
    float*          agg  = (float*)(ws + 25894912);                // 25.6 MB
    int*            perm = (int*)(ws + 51494912);                  // 3.2 MB
    int*            cnt  = (int*)(ws + 54694912);                  // 200 KB

    hipMemsetAsync(agg, 0, (size_t)NN * 128 * 4, stream);
    hipMemsetAsync(cnt, 0, (size_t)NN * 4, stream);

    k_wconv<<<36, 256, 0, stream>>>(Wsrc, Wdst, Wphi1, Wphi2, Wphi3,
                                    Wpd, Wpu, Wth1, Wth2, Wb);
    k_hist<<<1024, 256, 0, stream>>>(dst, cnt);
    k_scan<<<1, 1024, 0, stream>>>(cnt);
    k_perm<<<1024, 256, 0, stream>>>(dst, cnt, perm);
    k_nodepre<<<782, 256, 0, stream>>>(node_feat, Wb, bsrc, bdst, Asrc, Adst);
    k_edge<<<1024, 256, 0, stream>>>(edge_feat, node_feat, src, dst, perm,
                                     Asrc, Adst, Wb, bphi1, bphi2, bphi3, agg);
    k_nodeout<<<782, 256, 0, stream>>>(node_feat, agg, Wb, bpd, bpu, bth1, bth2,
                                       (float*)d_out);
}

// Round 3
// 787.525 us; speedup vs baseline: 1.1731x; 1.1731x over previous
//
#include <hip/hip_runtime.h>
#include <hip/hip_bf16.h>

#define NN 50000
#define NE 800000
#define NT_E 12500      // 800000 / 64
#define GRID_E 1536
#define NBLK_SCAN 196   // ceil(50000/256)

typedef __attribute__((ext_vector_type(8))) short bf16x8;
typedef __attribute__((ext_vector_type(4))) float f32x4;
typedef __attribute__((ext_vector_type(2))) float f32x2;
typedef __attribute__((ext_vector_type(8))) unsigned short u16x8;
typedef __attribute__((ext_vector_type(2))) unsigned short u16x2;

__device__ __forceinline__ unsigned short f2bf(float f) {
    union { float f; unsigned u; } v; v.f = f;
    unsigned r = v.u + 0x7FFFu + ((v.u >> 16) & 1u);   // RNE
    return (unsigned short)(r >> 16);
}
__device__ __forceinline__ float bf2f(unsigned short h) {
    union { unsigned u; float f; } v; v.u = ((unsigned)h) << 16;
    return v.f;
}
__device__ __forceinline__ f32x4 mfma16(bf16x8 a, bf16x8 b, f32x4 c) {
    return __builtin_amdgcn_mfma_f32_16x16x32_bf16(a, b, c, 0, 0, 0);
}
// barrier WITHOUT vmcnt drain: all cross-thread comm in k_edgeA is via LDS,
// so lgkmcnt(0)+s_barrier is sufficient; prefetch loads / Mbuf stores stay in flight.
__device__ __forceinline__ void syncl() {
    asm volatile("s_waitcnt lgkmcnt(0)\n\ts_barrier" ::: "memory");
}

__device__ __forceinline__ void load_wfrags(const unsigned short* __restrict__ Wb,
                                            int wv, int lane, bf16x8 (&wf)[4][2]) {
#pragma unroll
    for (int kk = 0; kk < 4; ++kk)
#pragma unroll
        for (int j = 0; j < 2; ++j) {
            int row = 32 * wv + 16 * j + (lane & 15);
            int col = 32 * kk + 8 * (lane >> 4);
            wf[kk][j] = *(const bf16x8*)(Wb + row * 128 + col);
        }
}

__device__ __forceinline__ void zero_acc(f32x4 (&acc)[4][2]) {
#pragma unroll
    for (int mt = 0; mt < 4; ++mt)
#pragma unroll
        for (int j = 0; j < 2; ++j) {
            f32x4 z = {0.f, 0.f, 0.f, 0.f};
            acc[mt][j] = z;
        }
}

__device__ __forceinline__ void gemm64(const unsigned short* __restrict__ X,
                                       const bf16x8 (&wf)[4][2], f32x4 (&acc)[4][2], int lane) {
#pragma unroll
    for (int kk = 0; kk < 4; ++kk) {
        bf16x8 a[4];
#pragma unroll
        for (int mt = 0; mt < 4; ++mt) {
            int row = mt * 16 + (lane & 15);
            a[mt] = *(const bf16x8*)(X + row * 136 + kk * 32 + 8 * (lane >> 4));
        }
#pragma unroll
        for (int mt = 0; mt < 4; ++mt) {
            acc[mt][0] = mfma16(a[mt], wf[kk][0], acc[mt][0]);
            acc[mt][1] = mfma16(a[mt], wf[kk][1], acc[mt][1]);
        }
    }
}

__device__ __forceinline__ void epi_lds(unsigned short* __restrict__ Xo,
                                        const f32x4 (&acc)[4][2],
                                        float bb0, float bb1, int c0, int rbase) {
#pragma unroll
    for (int mt = 0; mt < 4; ++mt)
#pragma unroll
        for (int r = 0; r < 4; ++r) {
            int row = mt * 16 + rbase + r;
            Xo[row * 136 + c0]      = f2bf(fmaxf(acc[mt][0][r] + bb0, 0.f));
            Xo[row * 136 + c0 + 16] = f2bf(fmaxf(acc[mt][1][r] + bb1, 0.f));
        }
}

__device__ __forceinline__ void stage_f32row(unsigned short* __restrict__ Xrow,
                                             const f32x4* __restrict__ p) {
#pragma unroll
    for (int i = 0; i < 4; ++i) {
        f32x4 lo = p[2 * i], hi = p[2 * i + 1];
        unsigned short tmp[8];
#pragma unroll
        for (int j = 0; j < 4; ++j) { tmp[j] = f2bf(lo[j]); tmp[4 + j] = f2bf(hi[j]); }
        *(u16x8*)(Xrow + i * 8) = *(u16x8*)tmp;
    }
}

// ================= kernel: convert 9 DxD fp32 weights to bf16 =================
__global__ void k_wconv(const float* w0, const float* w1, const float* w2,
                        const float* w3, const float* w4, const float* w5,
                        const float* w6, const float* w7, const float* w8,
                        unsigned short* out) {
    const float* ws[9] = {w0, w1, w2, w3, w4, w5, w6, w7, w8};
    int m = blockIdx.x >> 2;
    int part = blockIdx.x & 3;
    const float* w = ws[m] + part * 4096 + threadIdx.x * 16;
    unsigned short* o = out + m * 16384 + part * 4096 + threadIdx.x * 16;
    float f[16];
#pragma unroll
    for (int i = 0; i < 4; ++i) *(f32x4*)(f + 4 * i) = ((const f32x4*)w)[i];
    unsigned short tmp[16];
#pragma unroll
    for (int i = 0; i < 16; ++i) tmp[i] = f2bf(f[i]);
    ((u16x8*)o)[0] = *(u16x8*)tmp;
    ((u16x8*)o)[1] = *(u16x8*)(tmp + 8);
}

// ================= sort: hist -> 3-kernel scan -> inverse perm =================
__global__ void k_hist(const int* __restrict__ dst, int* __restrict__ cnt) {
    int i = blockIdx.x * 256 + threadIdx.x;
    if (i < NE) atomicAdd(&cnt[dst[i]], 1);
}

__global__ void k_scan1(const int* __restrict__ c, int* __restrict__ bsum) {
    __shared__ int red[256];
    int i = blockIdx.x * 256 + threadIdx.x;
    red[threadIdx.x] = (i < NN) ? c[i] : 0;
    __syncthreads();
    for (int off = 128; off > 0; off >>= 1) {
        if (threadIdx.x < off) red[threadIdx.x] += red[threadIdx.x + off];
        __syncthreads();
    }
    if (threadIdx.x == 0) bsum[blockIdx.x] = red[0];
}

__global__ void k_scan2(int* __restrict__ bsum) {   // 1 block, 256 threads
    __shared__ int s[256];
    int t = threadIdx.x;
    s[t] = (t < NBLK_SCAN) ? bsum[t] : 0;
    __syncthreads();
    for (int off = 1; off < 256; off <<= 1) {
        int v = (t >= off) ? s[t - off] : 0;
        __syncthreads();
        s[t] += v;
        __syncthreads();
    }
    if (t < NBLK_SCAN) bsum[t] = (t == 0) ? 0 : s[t - 1];
}

__global__ void k_scan3(int* __restrict__ cnt, const int* __restrict__ bsum,
                        int* __restrict__ rowptr) {
    __shared__ int s[256];
    int t = threadIdx.x;
    int i = blockIdx.x * 256 + t;
    int v = (i < NN) ? cnt[i] : 0;
    s[t] = v;
    __syncthreads();
    for (int off = 1; off < 256; off <<= 1) {
        int x = (t >= off) ? s[t - off] : 0;
        __syncthreads();
        s[t] += x;
        __syncthreads();
    }
    int excl = bsum[blockIdx.x] + s[t] - v;
    if (i < NN) { rowptr[i] = excl; cnt[i] = excl; }   // cnt becomes cursor
    if (i == 0) rowptr[NN] = NE;
}

__global__ void k_pos(const int* __restrict__ dst, int* __restrict__ cursor,
                      int* __restrict__ pos) {
    int i = blockIdx.x * 256 + threadIdx.x;
    if (i < NE) pos[i] = atomicAdd(&cursor[dst[i]], 1);
}

// ================= node pre: A_src, A_dst, Hb =================
__global__ __launch_bounds__(256, 3)
void k_nodepre(const float* __restrict__ h,
               const unsigned short* __restrict__ Wb,
               const float* __restrict__ bsrc, const float* __restrict__ bdst,
               unsigned short* __restrict__ Asrc, unsigned short* __restrict__ Adst,
               unsigned short* __restrict__ Hb) {
    __shared__ unsigned short X[64 * 136];
    int tid = threadIdx.x, lane = tid & 63, wv = tid >> 6;
    int n0 = blockIdx.x * 64;
    {
        int row = tid >> 2, q = tid & 3;
        int n = n0 + row;
        if (n < NN) {
            unsigned short tmp[32];
            const f32x4* hp = (const f32x4*)(h + (size_t)n * 128 + q * 32);
#pragma unroll
            for (int i = 0; i < 8; ++i) {
                f32x4 v = hp[i];
#pragma unroll
                for (int j = 0; j < 4; ++j) tmp[i * 4 + j] = f2bf(v[j]);
            }
#pragma unroll
            for (int i = 0; i < 4; ++i)
                *(u16x8*)(X + row * 136 + q * 32 + i * 8) = *(u16x8*)(tmp + i * 8);
            u16x8* hb = (u16x8*)(Hb + (size_t)n * 128 + q * 32);
#pragma unroll
            for (int i = 0; i < 4; ++i) hb[i] = *(u16x8*)(tmp + i * 8);
        } else {
            u16x8 z = {0, 0, 0, 0, 0, 0, 0, 0};
#pragma unroll
            for (int i = 0; i < 4; ++i) *(u16x8*)(X + row * 136 + q * 32 + i * 8) = z;
        }
    }
    __syncthreads();

    bf16x8 wfS[4][2], wfD[4][2];
    load_wfrags(Wb, wv, lane, wfS);
    load_wfrags(Wb + 16384, wv, lane, wfD);
    f32x4 accS[4][2], accD[4][2];
    zero_acc(accS); zero_acc(accD);
    gemm64(X, wfS, accS, lane);
    gemm64(X, wfD, accD, lane);

    int c0 = 32 * wv + (lane & 15);
    float bs0 = bsrc[c0], bs1 = bsrc[c0 + 16];
    float bd0 = bdst[c0], bd1 = bdst[c0 + 16];
    int rbase = (lane >> 4) * 4;
#pragma unroll
    for (int mt = 0; mt < 4; ++mt)
#pragma unroll
        for (int r = 0; r < 4; ++r) {
            int n = n0 + mt * 16 + rbase + r;
            if (n < NN) {
                size_t o = (size_t)n * 128;
                Asrc[o + c0]      = f2bf(accS[mt][0][r] + bs0);
                Asrc[o + c0 + 16] = f2bf(accS[mt][1][r] + bs1);
                Adst[o + c0]      = f2bf(accD[mt][0][r] + bd0);
                Adst[o + c0 + 16] = f2bf(accD[mt][1][r] + bd1);
            }
        }
}

// ============ edge MLP, natural order, prefetched, scatter-writes Mbuf =========
__global__ __launch_bounds__(256, 3)
void k_edgeA(const float* __restrict__ ef,
             const int* __restrict__ src, const int* __restrict__ dst,
             const int* __restrict__ pos,
             const unsigned short* __restrict__ Asrc,
             const unsigned short* __restrict__ Adst,
             const unsigned short* __restrict__ Hb,
             const unsigned short* __restrict__ Wb,
             const float* __restrict__ b1, const float* __restrict__ b2,
             const float* __restrict__ b3,
             unsigned short* __restrict__ Mbuf) {
    __shared__ __align__(16) char sh[52480];
    unsigned short* X0 = (unsigned short*)sh;             // [64][136]
    unsigned short* X1 = (unsigned short*)(sh + 17408);   // [64][136]
    unsigned short* Hs = (unsigned short*)(sh + 34816);   // [64][136]
    float*          Mf = (float*)sh;                      // [64][128] overlays X0+X1
    int*         posarr = (int*)(sh + 52224);             // [64]

    int tid = threadIdx.x, lane = tid & 63, wv = tid >> 6;

    bf16x8 wf1[4][2], wf2[4][2], wf3[4][2];
    load_wfrags(Wb + 2 * 16384, wv, lane, wf1);
    load_wfrags(Wb + 3 * 16384, wv, lane, wf2);
    load_wfrags(Wb + 4 * 16384, wv, lane, wf3);

    int c0 = 32 * wv + (lane & 15);
    float b1_0 = b1[c0], b1_1 = b1[c0 + 16];
    float b2_0 = b2[c0], b2_1 = b2[c0 + 16];
    float b3_0 = b3[c0], b3_1 = b3[c0 + 16];
    int rbase = (lane >> 4) * 4;
    int srow = tid >> 2, q = tid & 3;

    // prefetch state for tile "t" at top of iteration t
    int e_nx, s_nx, d_nx, p_nx;
    f32x4 efr[8];
    u16x8 asr[4], adr[4], hbr[4];

    auto load_idx = [&](int t) {
        int e = t * 64 + srow;
        e_nx = e;
        s_nx = src[e]; d_nx = dst[e]; p_nx = pos[e];
    };
    auto load_gather = [&]() {
        const f32x4* ep = (const f32x4*)(ef + (size_t)e_nx * 128 + q * 32);
#pragma unroll
        for (int i = 0; i < 8; ++i) efr[i] = ep[i];
        const u16x8* ap = (const u16x8*)(Asrc + (size_t)s_nx * 128 + q * 32);
        const u16x8* dp = (const u16x8*)(Adst + (size_t)d_nx * 128 + q * 32);
        const u16x8* hp = (const u16x8*)(Hb + (size_t)s_nx * 128 + q * 32);
#pragma unroll
        for (int i = 0; i < 4; ++i) { asr[i] = ap[i]; adr[i] = dp[i]; hbr[i] = hp[i]; }
    };

    int t0 = blockIdx.x;
    load_idx(t0);
    load_gather();

    for (int t = t0; t < NT_E; t += GRID_E) {
        int tn = t + GRID_E;
        syncl();                               // prev Mbuf-store done reading Mf/posarr
        {   // stage regs -> X0 (relu(e+as+ad)), Hs
#pragma unroll
            for (int i = 0; i < 4; ++i) {
                u16x8 a8 = asr[i], d8 = adr[i];
                f32x4 lo = efr[2 * i], hi = efr[2 * i + 1];
                unsigned short o[8];
#pragma unroll
                for (int j = 0; j < 8; ++j) {
                    float evv = (j < 4) ? lo[j] : hi[j - 4];
                    float v = evv + bf2f((unsigned short)a8[j]) + bf2f((unsigned short)d8[j]);
                    o[j] = f2bf(fmaxf(v, 0.f));
                }
                *(u16x8*)(X0 + srow * 136 + q * 32 + i * 8) = *(u16x8*)o;
                *(u16x8*)(Hs + srow * 136 + q * 32 + i * 8) = hbr[i];
            }
            if (q == 0) posarr[srow] = p_nx;
        }
        if (tn < NT_E) load_idx(tn);           // issue next idx loads early
        syncl();                               // X0/Hs/posarr visible
        if (tn < NT_E) load_gather();          // gathers fly under GEMM phase

        f32x4 acc[4][2];
        zero_acc(acc);
        gemm64(X0, wf1, acc, lane);
        syncl();                               // X0 reads done
        epi_lds(X1, acc, b1_0, b1_1, c0, rbase);
        syncl();                               // X1 ready
        zero_acc(acc);
        gemm64(X1, wf2, acc, lane);
        epi_lds(X0, acc, b2_0, b2_1, c0, rbase);
        syncl();                               // X0 ready
        zero_acc(acc);
        gemm64(X0, wf3, acc, lane);
        syncl();                               // all X0 (Mf region) reads done
        // m = h_src * (e_emb + b3) -> Mf fp32
#pragma unroll
        for (int mt = 0; mt < 4; ++mt)
#pragma unroll
            for (int r = 0; r < 4; ++r) {
                int row = mt * 16 + rbase + r;
                float h0 = bf2f(Hs[row * 136 + c0]);
                float h1 = bf2f(Hs[row * 136 + c0 + 16]);
                Mf[row * 128 + c0]      = (acc[mt][0][r] + b3_0) * h0;
                Mf[row * 128 + c0 + 16] = (acc[mt][1][r] + b3_1) * h1;
            }
        syncl();                               // Mf ready
        // coalesced row-store to sorted position: one 256B row per wave-inst
#pragma unroll
        for (int i = 0; i < 16; ++i) {
            int row = wv * 16 + i;
            int posr = posarr[row];
            f32x2 v = *(const f32x2*)(Mf + row * 128 + lane * 2);
            u16x2 o2; o2[0] = f2bf(v[0]); o2[1] = f2bf(v[1]);
            *(u16x2*)(Mbuf + (size_t)posr * 128 + lane * 2) = o2;
        }
    }
}

// ============ aggregate: one wave per node, sequential Mbuf rows ==============
__global__ __launch_bounds__(256)
void k_agg(const unsigned short* __restrict__ Mbuf,
           const int* __restrict__ rowptr, float* __restrict__ agg) {
    int n = (blockIdx.x * 256 + threadIdx.x) >> 6;
    int lane = threadIdx.x & 63;
    if (n >= NN) return;
    int j0 = rowptr[n], j1 = rowptr[n + 1];
    float a0 = 0.f, a1 = 0.f;
    int j = j0;
    for (; j + 3 < j1; j += 4) {
        u16x2 v0 = *(const u16x2*)(Mbuf + (size_t)j * 128 + lane * 2);
        u16x2 v1 = *(const u16x2*)(Mbuf + (size_t)(j + 1) * 128 + lane * 2);
        u16x2 v2 = *(const u16x2*)(Mbuf + (size_t)(j + 2) * 128 + lane * 2);
        u16x2 v3 = *(const u16x2*)(Mbuf + (size_t)(j + 3) * 128 + lane * 2);
        a0 += bf2f(v0[0]) + bf2f(v1[0]) + bf2f(v2[0]) + bf2f(v3[0]);
        a1 += bf2f(v0[1]) + bf2f(v1[1]) + bf2f(v2[1]) + bf2f(v3[1]);
    }
    for (; j < j1; ++j) {
        u16x2 v = *(const u16x2*)(Mbuf + (size_t)j * 128 + lane * 2);
        a0 += bf2f(v[0]); a1 += bf2f(v[1]);
    }
    f32x2 o; o[0] = a0; o[1] = a1;
    *(f32x2*)(agg + (size_t)n * 128 + lane * 2) = o;
}

// ============ fallback edge kernel (R1-style direct atomics) ==================
__global__ __launch_bounds__(256, 2)
void k_edge_atomic(const float* __restrict__ ef,
                   const int* __restrict__ src, const int* __restrict__ dst,
                   const unsigned short* __restrict__ Asrc,
                   const unsigned short* __restrict__ Adst,
                   const unsigned short* __restrict__ Hb,
                   const unsigned short* __restrict__ Wb,
                   const float* __restrict__ b1, const float* __restrict__ b2,
                   const float* __restrict__ b3,
                   float* __restrict__ agg) {
    __shared__ unsigned short X0[64 * 136];
    __shared__ unsigned short X1[64 * 136];
    __shared__ unsigned short Hs[64 * 136];
    __shared__ int soff_lds[64];
    __shared__ int doff_lds[64];

    int tid = threadIdx.x, lane = tid & 63, wv = tid >> 6;
    bf16x8 wf1[4][2], wf2[4][2], wf3[4][2];
    load_wfrags(Wb + 2 * 16384, wv, lane, wf1);
    load_wfrags(Wb + 3 * 16384, wv, lane, wf2);
    load_wfrags(Wb + 4 * 16384, wv, lane, wf3);

    int c0 = 32 * wv + (lane & 15);
    float b1_0 = b1[c0], b1_1 = b1[c0 + 16];
    float b2_0 = b2[c0], b2_1 = b2[c0 + 16];
    float b3_0 = b3[c0], b3_1 = b3[c0 + 16];
    int rbase = (lane >> 4) * 4;
    int srow = tid >> 2, q = tid & 3;

    for (int t = blockIdx.x; t < NT_E; t += gridDim.x) {
        int e0 = t * 64;
        __syncthreads();
        if (tid < 64) {
            soff_lds[tid] = src[e0 + tid] * 128;
            doff_lds[tid] = dst[e0 + tid] * 128;
        }
        __syncthreads();
        {
            int so = soff_lds[srow], dofs = doff_lds[srow];
            const f32x4* ep = (const f32x4*)(ef + (size_t)(e0 + srow) * 128 + q * 32);
            const u16x8* ap = (const u16x8*)(Asrc + so + q * 32);
            const u16x8* dp = (const u16x8*)(Adst + dofs + q * 32);
            const u16x8* hp = (const u16x8*)(Hb + so + q * 32);
#pragma unroll
            for (int i = 0; i < 4; ++i) {
                u16x8 a8 = ap[i], d8 = dp[i], h8 = hp[i];
                f32x4 e_lo = ep[2 * i], e_hi = ep[2 * i + 1];
                unsigned short o[8];
#pragma unroll
                for (int j = 0; j < 8; ++j) {
                    float evv = (j < 4) ? e_lo[j] : e_hi[j - 4];
                    float v = evv + bf2f((unsigned short)a8[j]) + bf2f((unsigned short)d8[j]);
                    o[j] = f2bf(fmaxf(v, 0.f));
                }
                *(u16x8*)(X0 + srow * 136 + q * 32 + i * 8) = *(u16x8*)o;
                *(u16x8*)(Hs + srow * 136 + q * 32 + i * 8) = h8;
            }
        }
        __syncthreads();
        f32x4 acc[4][2];
        zero_acc(acc);
        gemm64(X0, wf1, acc, lane);
        __syncthreads();
        epi_lds(X1, acc, b1_0, b1_1, c0, rbase);
        __syncthreads();
        zero_acc(acc);
        gemm64(X1, wf2, acc, lane);
        epi_lds(X0, acc, b2_0, b2_1, c0, rbase);
        __syncthreads();
        zero_acc(acc);
        gemm64(X0, wf3, acc, lane);
#pragma unroll
        for (int mt = 0; mt < 4; ++mt)
#pragma unroll
            for (int r = 0; r < 4; ++r) {
                int row = mt * 16 + rbase + r;
                int dofs = doff_lds[row];
                float h0 = bf2f(Hs[row * 136 + c0]);
                float h1 = bf2f(Hs[row * 136 + c0 + 16]);
                atomicAdd(agg + dofs + c0,      (acc[mt][0][r] + b3_0) * h0);
                atomicAdd(agg + dofs + c0 + 16, (acc[mt][1][r] + b3_1) * h1);
            }
    }
}

// ================= node output =================
__global__ __launch_bounds__(256, 3)
void k_nodeout(const unsigned short* __restrict__ Hb,
               const float* __restrict__ agg,
               const unsigned short* __restrict__ Wb,
               const float* __restrict__ bpd, const float* __restrict__ bpu,
               const float* __restrict__ bt1, const float* __restrict__ bt2,
               float* __restrict__ out) {
    __shared__ unsigned short Xh[64 * 136];
    __shared__ unsigned short Xa[64 * 136];
    int tid = threadIdx.x, lane = tid & 63, wv = tid >> 6;
    int n0 = blockIdx.x * 64;
    {
        int row = tid >> 2, q = tid & 3;
        int n = n0 + row;
        if (n < NN) {
            const u16x8* hp = (const u16x8*)(Hb + (size_t)n * 128 + q * 32);
#pragma unroll
            for (int i = 0; i < 4; ++i)
                *(u16x8*)(Xh + row * 136 + q * 32 + i * 8) = hp[i];
            stage_f32row(Xa + row * 136 + q * 32,
                         (const f32x4*)(agg + (size_t)n * 128 + q * 32));
        } else {
            u16x8 z = {0, 0, 0, 0, 0, 0, 0, 0};
#pragma unroll
            for (int i = 0; i < 4; ++i) {
                *(u16x8*)(Xh + row * 136 + q * 32 + i * 8) = z;
                *(u16x8*)(Xa + row * 136 + q * 32 + i * 8) = z;
            }
        }
    }
    __syncthreads();
    bf16x8 wfa[4][2], wfb[4][2];
    load_wfrags(Wb + 5 * 16384, wv, lane, wfa);   // Wpd
    load_wfrags(Wb + 6 * 16384, wv, lane, wfb);   // Wpu
    int c0 = 32 * wv + (lane & 15);
    int rbase = (lane >> 4) * 4;
    f32x4 acc[4][2];
    zero_acc(acc);
    gemm64(Xh, wfa, acc, lane);
    gemm64(Xa, wfb, acc, lane);
    float bb0 = bpd[c0] + bpu[c0], bb1 = bpd[c0 + 16] + bpu[c0 + 16];
    __syncthreads();
    epi_lds(Xh, acc, bb0, bb1, c0, rbase);
    __syncthreads();
    load_wfrags(Wb + 7 * 16384, wv, lane, wfa);   // Wth1
    zero_acc(acc);
    gemm64(Xh, wfa, acc, lane);
    float b10 = bt1[c0], b11 = bt1[c0 + 16];
    __syncthreads();
    epi_lds(Xa, acc, b10, b11, c0, rbase);
    __syncthreads();
    load_wfrags(Wb + 8 * 16384, wv, lane, wfb);   // Wth2
    zero_acc(acc);
    gemm64(Xa, wfb, acc, lane);
    float b20 = bt2[c0], b21 = bt2[c0 + 16];
#pragma unroll
    for (int mt = 0; mt < 4; ++mt)
#pragma unroll
        for (int r = 0; r < 4; ++r) {
            int n = n0 + mt * 16 + rbase + r;
            if (n < NN) {
                out[(size_t)n * 128 + c0]      = acc[mt][0][r] + b20;
                out[(size_t)n * 128 + c0 + 16] = acc[mt][1][r] + b21;
            }
        }
}

extern "C" void kernel_launch(void* const* d_in, const int* in_sizes, int n_in,
                              void* d_out, int out_size, void* d_ws, size_t ws_size,
                              hipStream_t stream) {
    (void)in_sizes; (void)n_in; (void)out_size;
    const float* node_feat = (const float*)d_in[0];
    const float* edge_feat = (const float*)d_in[1];
    const int*   src  = (const int*)d_in[2];
    const int*   dst  = (const int*)d_in[3];
    const float* Wsrc = (const float*)d_in[4];  const float* bsrc = (const float*)d_in[5];
    const float* Wdst = (const float*)d_in[6];  const float* bdst = (const float*)d_in[7];
    const float* Wphi1 = (const float*)d_in[8]; const float* bphi1 = (const float*)d_in[9];
    const float* Wphi2 = (const float*)d_in[10];const float* bphi2 = (const float*)d_in[11];
    const float* Wphi3 = (const float*)d_in[12];const float* bphi3 = (const float*)d_in[13];
    const float* Wth1 = (const float*)d_in[14]; const float* bth1 = (const float*)d_in[15];
    const float* Wth2 = (const float*)d_in[16]; const float* bth2 = (const float*)d_in[17];
    const float* Wpd  = (const float*)d_in[18]; const float* bpd  = (const float*)d_in[19];
    const float* Wpu  = (const float*)d_in[20]; const float* bpu  = (const float*)d_in[21];

    // workspace carve
    char* ws = (char*)d_ws;
    size_t off = 0;
    unsigned short* Wb   = (unsigned short*)(ws + off); off += 294912;
    unsigned short* Asrc = (unsigned short*)(ws + off); off += 12800000;
    unsigned short* Adst = (unsigned short*)(ws + off); off += 12800000;
    unsigned short* Hb   = (unsigned short*)(ws + off); off += 12800000;
    float*          agg  = (float*)(ws + off);          off += 25600000;
    int*            cnt  = (int*)(ws + off);            off += 200064;
    int*            rowptr = (int*)(ws + off);          off += 200064;
    int*            bsum = (int*)(ws + off);            off += 1024;
    int*            pos  = (int*)(ws + off);            off += 3200000;
    unsigned short* Mbuf = (unsigned short*)(ws + off); off += 204800000;
    bool primary = (ws_size >= off);

    k_wconv<<<36, 256, 0, stream>>>(Wsrc, Wdst, Wphi1, Wphi2, Wphi3,
                                    Wpd, Wpu, Wth1, Wth2, Wb);
    k_nodepre<<<782, 256, 0, stream>>>(node_feat, Wb, bsrc, bdst, Asrc, Adst, Hb);

    if (primary) {
        hipMemsetAsync(cnt, 0, (size_t)NN * 4, stream);
        k_hist<<<3125, 256, 0, stream>>>(dst, cnt);
        k_scan1<<<NBLK_SCAN, 256, 0, stream>>>(cnt, bsum);
        k_scan2<<<1, 256, 0, stream>>>(bsum);
        k_scan3<<<NBLK_SCAN, 256, 0, stream>>>(cnt, bsum, rowptr);
        k_pos<<<3125, 256, 0, stream>>>(dst, cnt, pos);
        k_edgeA<<<GRID_E, 256, 0, stream>>>(edge_feat, src, dst, pos,
                                            Asrc, Adst, Hb, Wb,
                                            bphi1, bphi2, bphi3, Mbuf);
        k_agg<<<(NN * 64 + 255) / 256, 256, 0, stream>>>(Mbuf, rowptr, agg);
    } else {
        hipMemsetAsync(agg, 0, (size_t)NN * 128 * 4, stream);
        k_edge_atomic<<<1024, 256, 0, stream>>>(edge_feat, src, dst,
                                                Asrc, Adst, Hb, Wb,
                                                bphi1, bphi2, bphi3, agg);
    }
    k_nodeout<<<782, 256, 0, stream>>>(Hb, agg, Wb, bpd, bpu, bth1, bth2,
                                       (float*)d_out);
}

// Round 4
// 510.893 us; speedup vs baseline: 1.8083x; 1.5415x over previous
//
#include <hip/hip_runtime.h>
#include <hip/hip_bf16.h>

#define NN 50000
#define NE 800000
#define NT_E 12500      // 800000 / 64
#define GRID_E 768
#define NBLK_SCAN 196   // ceil(50000/256)

typedef __attribute__((ext_vector_type(8))) short bf16x8;
typedef __attribute__((ext_vector_type(4))) float f32x4;
typedef __attribute__((ext_vector_type(2))) float f32x2;
typedef __attribute__((ext_vector_type(8))) unsigned short u16x8;
typedef __attribute__((ext_vector_type(2))) unsigned short u16x2;

__device__ __forceinline__ unsigned short f2bf(float f) {
    union { float f; unsigned u; } v; v.f = f;
    unsigned r = v.u + 0x7FFFu + ((v.u >> 16) & 1u);   // RNE
    return (unsigned short)(r >> 16);
}
__device__ __forceinline__ float bf2f(unsigned short h) {
    union { unsigned u; float f; } v; v.u = ((unsigned)h) << 16;
    return v.f;
}
__device__ __forceinline__ f32x4 mfma16(bf16x8 a, bf16x8 b, f32x4 c) {
    return __builtin_amdgcn_mfma_f32_16x16x32_bf16(a, b, c, 0, 0, 0);
}
// barrier WITHOUT vmcnt drain: cross-thread comm is via LDS only, so
// lgkmcnt(0)+s_barrier suffices; global loads/stores stay in flight.
__device__ __forceinline__ void syncl() {
    asm volatile("s_waitcnt lgkmcnt(0)\n\ts_barrier" ::: "memory");
}

__device__ __forceinline__ void load_wfrags(const unsigned short* __restrict__ Wb,
                                            int wv, int lane, bf16x8 (&wf)[4][2]) {
#pragma unroll
    for (int kk = 0; kk < 4; ++kk)
#pragma unroll
        for (int j = 0; j < 2; ++j) {
            int row = 32 * wv + 16 * j + (lane & 15);
            int col = 32 * kk + 8 * (lane >> 4);
            wf[kk][j] = *(const bf16x8*)(Wb + row * 128 + col);
        }
}

__device__ __forceinline__ void zero_acc(f32x4 (&acc)[4][2]) {
#pragma unroll
    for (int mt = 0; mt < 4; ++mt)
#pragma unroll
        for (int j = 0; j < 2; ++j) {
            f32x4 z = {0.f, 0.f, 0.f, 0.f};
            acc[mt][j] = z;
        }
}

__device__ __forceinline__ void gemm64(const unsigned short* __restrict__ X,
                                       const bf16x8 (&wf)[4][2], f32x4 (&acc)[4][2], int lane) {
#pragma unroll
    for (int kk = 0; kk < 4; ++kk) {
        bf16x8 a[4];
#pragma unroll
        for (int mt = 0; mt < 4; ++mt) {
            int row = mt * 16 + (lane & 15);
            a[mt] = *(const bf16x8*)(X + row * 136 + kk * 32 + 8 * (lane >> 4));
        }
#pragma unroll
        for (int mt = 0; mt < 4; ++mt) {
            acc[mt][0] = mfma16(a[mt], wf[kk][0], acc[mt][0]);
            acc[mt][1] = mfma16(a[mt], wf[kk][1], acc[mt][1]);
        }
    }
}

__device__ __forceinline__ void epi_lds(unsigned short* __restrict__ Xo,
                                        const f32x4 (&acc)[4][2],
                                        float bb0, float bb1, int c0, int rbase) {
#pragma unroll
    for (int mt = 0; mt < 4; ++mt)
#pragma unroll
        for (int r = 0; r < 4; ++r) {
            int row = mt * 16 + rbase + r;
            Xo[row * 136 + c0]      = f2bf(fmaxf(acc[mt][0][r] + bb0, 0.f));
            Xo[row * 136 + c0 + 16] = f2bf(fmaxf(acc[mt][1][r] + bb1, 0.f));
        }
}

__device__ __forceinline__ void stage_f32row(unsigned short* __restrict__ Xrow,
                                             const f32x4* __restrict__ p) {
#pragma unroll
    for (int i = 0; i < 4; ++i) {
        f32x4 lo = p[2 * i], hi = p[2 * i + 1];
        unsigned short tmp[8];
#pragma unroll
        for (int j = 0; j < 4; ++j) { tmp[j] = f2bf(lo[j]); tmp[4 + j] = f2bf(hi[j]); }
        *(u16x8*)(Xrow + i * 8) = *(u16x8*)tmp;
    }
}

// ================= convert 9 DxD fp32 weights to bf16 =================
__global__ void k_wconv(const float* w0, const float* w1, const float* w2,
                        const float* w3, const float* w4, const float* w5,
                        const float* w6, const float* w7, const float* w8,
                        unsigned short* out) {
    const float* ws[9] = {w0, w1, w2, w3, w4, w5, w6, w7, w8};
    int m = blockIdx.x >> 2;
    int part = blockIdx.x & 3;
    const float* w = ws[m] + part * 4096 + threadIdx.x * 16;
    unsigned short* o = out + m * 16384 + part * 4096 + threadIdx.x * 16;
    float f[16];
#pragma unroll
    for (int i = 0; i < 4; ++i) *(f32x4*)(f + 4 * i) = ((const f32x4*)w)[i];
    unsigned short tmp[16];
#pragma unroll
    for (int i = 0; i < 16; ++i) tmp[i] = f2bf(f[i]);
    ((u16x8*)o)[0] = *(u16x8*)tmp;
    ((u16x8*)o)[1] = *(u16x8*)(tmp + 8);
}

// ================= sort: hist -> 3-kernel scan -> position =================
__global__ void k_hist(const int* __restrict__ dst, int* __restrict__ cnt) {
    int i = blockIdx.x * 256 + threadIdx.x;
    if (i < NE) atomicAdd(&cnt[dst[i]], 1);
}

__global__ void k_scan1(const int* __restrict__ c, int* __restrict__ bsum) {
    __shared__ int red[256];
    int i = blockIdx.x * 256 + threadIdx.x;
    red[threadIdx.x] = (i < NN) ? c[i] : 0;
    __syncthreads();
    for (int off = 128; off > 0; off >>= 1) {
        if (threadIdx.x < off) red[threadIdx.x] += red[threadIdx.x + off];
        __syncthreads();
    }
    if (threadIdx.x == 0) bsum[blockIdx.x] = red[0];
}

__global__ void k_scan2(int* __restrict__ bsum) {   // 1 block, 256 threads
    __shared__ int s[256];
    int t = threadIdx.x;
    s[t] = (t < NBLK_SCAN) ? bsum[t] : 0;
    __syncthreads();
    for (int off = 1; off < 256; off <<= 1) {
        int v = (t >= off) ? s[t - off] : 0;
        __syncthreads();
        s[t] += v;
        __syncthreads();
    }
    if (t < NBLK_SCAN) bsum[t] = (t == 0) ? 0 : s[t - 1];
}

__global__ void k_scan3(int* __restrict__ cnt, const int* __restrict__ bsum,
                        int* __restrict__ rowptr) {
    __shared__ int s[256];
    int t = threadIdx.x;
    int i = blockIdx.x * 256 + t;
    int v = (i < NN) ? cnt[i] : 0;
    s[t] = v;
    __syncthreads();
    for (int off = 1; off < 256; off <<= 1) {
        int x = (t >= off) ? s[t - off] : 0;
        __syncthreads();
        s[t] += x;
        __syncthreads();
    }
    int excl = bsum[blockIdx.x] + s[t] - v;
    if (i < NN) { rowptr[i] = excl; cnt[i] = excl; }   // cnt becomes cursor
    if (i == 0) rowptr[NN] = NE;
}

__global__ void k_pos(const int* __restrict__ dst, int* __restrict__ cursor,
                      int* __restrict__ pos) {
    int i = blockIdx.x * 256 + threadIdx.x;
    if (i < NE) pos[i] = atomicAdd(&cursor[dst[i]], 1);
}

// ================= node pre: AH = [Asrc row | Hb row], Adst =================
__global__ __launch_bounds__(256, 3)
void k_nodepre(const float* __restrict__ h,
               const unsigned short* __restrict__ Wb,
               const float* __restrict__ bsrc, const float* __restrict__ bdst,
               unsigned short* __restrict__ AH, unsigned short* __restrict__ Adst) {
    __shared__ unsigned short X[64 * 136];
    int tid = threadIdx.x, lane = tid & 63, wv = tid >> 6;
    int n0 = blockIdx.x * 64;
    {
        int row = tid >> 2, q = tid & 3;
        int n = n0 + row;
        if (n < NN) {
            unsigned short tmp[32];
            const f32x4* hp = (const f32x4*)(h + (size_t)n * 128 + q * 32);
#pragma unroll
            for (int i = 0; i < 8; ++i) {
                f32x4 v = hp[i];
#pragma unroll
                for (int j = 0; j < 4; ++j) tmp[i * 4 + j] = f2bf(v[j]);
            }
#pragma unroll
            for (int i = 0; i < 4; ++i)
                *(u16x8*)(X + row * 136 + q * 32 + i * 8) = *(u16x8*)(tmp + i * 8);
            u16x8* hb = (u16x8*)(AH + (size_t)n * 256 + 128 + q * 32);
#pragma unroll
            for (int i = 0; i < 4; ++i) hb[i] = *(u16x8*)(tmp + i * 8);
        } else {
            u16x8 z = {0, 0, 0, 0, 0, 0, 0, 0};
#pragma unroll
            for (int i = 0; i < 4; ++i) *(u16x8*)(X + row * 136 + q * 32 + i * 8) = z;
        }
    }
    __syncthreads();

    bf16x8 wfS[4][2], wfD[4][2];
    load_wfrags(Wb, wv, lane, wfS);
    load_wfrags(Wb + 16384, wv, lane, wfD);
    f32x4 accS[4][2], accD[4][2];
    zero_acc(accS); zero_acc(accD);
    gemm64(X, wfS, accS, lane);
    gemm64(X, wfD, accD, lane);

    int c0 = 32 * wv + (lane & 15);
    float bs0 = bsrc[c0], bs1 = bsrc[c0 + 16];
    float bd0 = bdst[c0], bd1 = bdst[c0 + 16];
    int rbase = (lane >> 4) * 4;
#pragma unroll
    for (int mt = 0; mt < 4; ++mt)
#pragma unroll
        for (int r = 0; r < 4; ++r) {
            int n = n0 + mt * 16 + rbase + r;
            if (n < NN) {
                AH[(size_t)n * 256 + c0]        = f2bf(accS[mt][0][r] + bs0);
                AH[(size_t)n * 256 + c0 + 16]   = f2bf(accS[mt][1][r] + bs1);
                Adst[(size_t)n * 128 + c0]      = f2bf(accD[mt][0][r] + bd0);
                Adst[(size_t)n * 128 + c0 + 16] = f2bf(accD[mt][1][r] + bd1);
            }
        }
}

// ===== edge MLP, natural order, LDS staging, scatter-writes Mbuf at pos =====
__global__ __launch_bounds__(256, 3)
void k_edgeB(const float* __restrict__ ef,
             const int* __restrict__ src, const int* __restrict__ dst,
             const int* __restrict__ pos,
             const unsigned short* __restrict__ AH,
             const unsigned short* __restrict__ Adst,
             const unsigned short* __restrict__ Wb,
             const float* __restrict__ b1, const float* __restrict__ b2,
             const float* __restrict__ b3,
             unsigned short* __restrict__ Mbuf) {
    __shared__ __align__(16) char sh[52480];
    unsigned short* X0 = (unsigned short*)sh;             // [64][136]
    unsigned short* X1 = (unsigned short*)(sh + 17408);   // [64][136]
    unsigned short* Hs = (unsigned short*)(sh + 34816);   // [64][136]
    float*          Mf = (float*)sh;                      // [64][128] overlays X0+X1
    int*         posarr = (int*)(sh + 52224);             // [64]

    int tid = threadIdx.x, lane = tid & 63, wv = tid >> 6;

    // only wf1/wf2 resident; wf3 reloaded per tile (keeps VGPR under (256,3) cap)
    bf16x8 wf1[4][2], wf2[4][2];
    load_wfrags(Wb + 2 * 16384, wv, lane, wf1);
    load_wfrags(Wb + 3 * 16384, wv, lane, wf2);

    int c0 = 32 * wv + (lane & 15);
    float b1_0 = b1[c0], b1_1 = b1[c0 + 16];
    float b2_0 = b2[c0], b2_1 = b2[c0 + 16];
    float b3_0 = b3[c0], b3_1 = b3[c0 + 16];
    int rbase = (lane >> 4) * 4;
    int srow = tid >> 2, q = tid & 3;

    // contiguous chunk per block: ef stream stays sequential per block
    int b = blockIdx.x, nb = gridDim.x;
    int qt = NT_E / nb, rt = NT_E % nb;
    int t0 = (b < rt) ? b * (qt + 1) : rt * (qt + 1) + (b - rt) * qt;
    int t1 = t0 + ((b < rt) ? qt + 1 : qt);

    for (int t = t0; t < t1; ++t) {
        int e0 = t * 64;
        syncl();                               // prev Mbuf-phase LDS reads done
        {   // stage: X0 = relu(ef + AH.a[src] + Adst[dst]), Hs = AH.h[src]
            int e = e0 + srow;
            int s = src[e], d = dst[e];
            if (q == 0) posarr[srow] = pos[e];
            const f32x4* ep = (const f32x4*)(ef + (size_t)e * 128 + q * 32);
            const u16x8* ap = (const u16x8*)(AH + (size_t)s * 256 + q * 32);
            const u16x8* hp = (const u16x8*)(AH + (size_t)s * 256 + 128 + q * 32);
            const u16x8* dp = (const u16x8*)(Adst + (size_t)d * 128 + q * 32);
#pragma unroll
            for (int i = 0; i < 4; ++i) {
                u16x8 a8 = ap[i], d8 = dp[i], h8 = hp[i];
                f32x4 lo = ep[2 * i], hi = ep[2 * i + 1];
                unsigned short o[8];
#pragma unroll
                for (int j = 0; j < 8; ++j) {
                    float evv = (j < 4) ? lo[j] : hi[j - 4];
                    float v = evv + bf2f((unsigned short)a8[j]) + bf2f((unsigned short)d8[j]);
                    o[j] = f2bf(fmaxf(v, 0.f));
                }
                *(u16x8*)(X0 + srow * 136 + q * 32 + i * 8) = *(u16x8*)o;
                *(u16x8*)(Hs + srow * 136 + q * 32 + i * 8) = h8;
            }
        }
        syncl();                               // X0/Hs/posarr visible
        f32x4 acc[4][2];
        zero_acc(acc);
        gemm64(X0, wf1, acc, lane);
        syncl();                               // X0 reads done
        epi_lds(X1, acc, b1_0, b1_1, c0, rbase);
        syncl();                               // X1 ready
        zero_acc(acc);
        gemm64(X1, wf2, acc, lane);
        epi_lds(X0, acc, b2_0, b2_1, c0, rbase);
        syncl();                               // X0 ready
        bf16x8 wf3[4][2];
        load_wfrags(Wb + 4 * 16384, wv, lane, wf3);   // L1/L2-hot reload
        zero_acc(acc);
        gemm64(X0, wf3, acc, lane);
        syncl();                               // all X0 (Mf region) reads done
        // m = h_src * (e_emb + b3) -> Mf fp32 (column slice per wave)
#pragma unroll
        for (int mt = 0; mt < 4; ++mt)
#pragma unroll
            for (int r = 0; r < 4; ++r) {
                int row = mt * 16 + rbase + r;
                float h0 = bf2f(Hs[row * 136 + c0]);
                float h1 = bf2f(Hs[row * 136 + c0 + 16]);
                Mf[row * 128 + c0]      = (acc[mt][0][r] + b3_0) * h0;
                Mf[row * 128 + c0 + 16] = (acc[mt][1][r] + b3_1) * h1;
            }
        syncl();                               // Mf ready
        // coalesced 256B row store to dst-sorted position
#pragma unroll
        for (int i = 0; i < 16; ++i) {
            int row = wv * 16 + i;
            int posr = posarr[row];
            f32x2 v = *(const f32x2*)(Mf + row * 128 + lane * 2);
            u16x2 o2; o2[0] = f2bf(v[0]); o2[1] = f2bf(v[1]);
            *(u16x2*)(Mbuf + (size_t)posr * 128 + lane * 2) = o2;
        }
    }
}

// ============ aggregate: one wave per node, sequential Mbuf rows ==============
__global__ __launch_bounds__(256)
void k_agg(const unsigned short* __restrict__ Mbuf,
           const int* __restrict__ rowptr, float* __restrict__ agg) {
    int n = (blockIdx.x * 256 + threadIdx.x) >> 6;
    int lane = threadIdx.x & 63;
    if (n >= NN) return;
    int j0 = rowptr[n], j1 = rowptr[n + 1];
    float a0 = 0.f, a1 = 0.f;
    int j = j0;
    for (; j + 3 < j1; j += 4) {
        u16x2 v0 = *(const u16x2*)(Mbuf + (size_t)j * 128 + lane * 2);
        u16x2 v1 = *(const u16x2*)(Mbuf + (size_t)(j + 1) * 128 + lane * 2);
        u16x2 v2 = *(const u16x2*)(Mbuf + (size_t)(j + 2) * 128 + lane * 2);
        u16x2 v3 = *(const u16x2*)(Mbuf + (size_t)(j + 3) * 128 + lane * 2);
        a0 += bf2f(v0[0]) + bf2f(v1[0]) + bf2f(v2[0]) + bf2f(v3[0]);
        a1 += bf2f(v0[1]) + bf2f(v1[1]) + bf2f(v2[1]) + bf2f(v3[1]);
    }
    for (; j < j1; ++j) {
        u16x2 v = *(const u16x2*)(Mbuf + (size_t)j * 128 + lane * 2);
        a0 += bf2f(v[0]); a1 += bf2f(v[1]);
    }
    f32x2 o; o[0] = a0; o[1] = a1;
    *(f32x2*)(agg + (size_t)n * 128 + lane * 2) = o;
}

// ============ fallback edge kernel (direct atomics, small-ws path) ============
__global__ __launch_bounds__(256, 2)
void k_edge_atomic(const float* __restrict__ ef,
                   const int* __restrict__ src, const int* __restrict__ dst,
                   const unsigned short* __restrict__ AH,
                   const unsigned short* __restrict__ Adst,
                   const unsigned short* __restrict__ Wb,
                   const float* __restrict__ b1, const float* __restrict__ b2,
                   const float* __restrict__ b3,
                   float* __restrict__ agg) {
    __shared__ unsigned short X0[64 * 136];
    __shared__ unsigned short X1[64 * 136];
    __shared__ unsigned short Hs[64 * 136];
    __shared__ int doff_lds[64];

    int tid = threadIdx.x, lane = tid & 63, wv = tid >> 6;
    bf16x8 wf1[4][2], wf2[4][2], wf3[4][2];
    load_wfrags(Wb + 2 * 16384, wv, lane, wf1);
    load_wfrags(Wb + 3 * 16384, wv, lane, wf2);
    load_wfrags(Wb + 4 * 16384, wv, lane, wf3);

    int c0 = 32 * wv + (lane & 15);
    float b1_0 = b1[c0], b1_1 = b1[c0 + 16];
    float b2_0 = b2[c0], b2_1 = b2[c0 + 16];
    float b3_0 = b3[c0], b3_1 = b3[c0 + 16];
    int rbase = (lane >> 4) * 4;
    int srow = tid >> 2, q = tid & 3;

    for (int t = blockIdx.x; t < NT_E; t += gridDim.x) {
        int e0 = t * 64;
        __syncthreads();
        {
            int e = e0 + srow;
            int s = src[e], d = dst[e];
            if (q == 0) doff_lds[srow] = d * 128;
            const f32x4* ep = (const f32x4*)(ef + (size_t)e * 128 + q * 32);
            const u16x8* ap = (const u16x8*)(AH + (size_t)s * 256 + q * 32);
            const u16x8* hp = (const u16x8*)(AH + (size_t)s * 256 + 128 + q * 32);
            const u16x8* dp = (const u16x8*)(Adst + (size_t)d * 128 + q * 32);
#pragma unroll
            for (int i = 0; i < 4; ++i) {
                u16x8 a8 = ap[i], d8 = dp[i], h8 = hp[i];
                f32x4 lo = ep[2 * i], hi = ep[2 * i + 1];
                unsigned short o[8];
#pragma unroll
                for (int j = 0; j < 8; ++j) {
                    float evv = (j < 4) ? lo[j] : hi[j - 4];
                    float v = evv + bf2f((unsigned short)a8[j]) + bf2f((unsigned short)d8[j]);
                    o[j] = f2bf(fmaxf(v, 0.f));
                }
                *(u16x8*)(X0 + srow * 136 + q * 32 + i * 8) = *(u16x8*)o;
                *(u16x8*)(Hs + srow * 136 + q * 32 + i * 8) = h8;
            }
        }
        __syncthreads();
        f32x4 acc[4][2];
        zero_acc(acc);
        gemm64(X0, wf1, acc, lane);
        __syncthreads();
        epi_lds(X1, acc, b1_0, b1_1, c0, rbase);
        __syncthreads();
        zero_acc(acc);
        gemm64(X1, wf2, acc, lane);
        epi_lds(X0, acc, b2_0, b2_1, c0, rbase);
        __syncthreads();
        zero_acc(acc);
        gemm64(X0, wf3, acc, lane);
#pragma unroll
        for (int mt = 0; mt < 4; ++mt)
#pragma unroll
            for (int r = 0; r < 4; ++r) {
                int row = mt * 16 + rbase + r;
                int dofs = doff_lds[row];
                float h0 = bf2f(Hs[row * 136 + c0]);
                float h1 = bf2f(Hs[row * 136 + c0 + 16]);
                atomicAdd(agg + dofs + c0,      (acc[mt][0][r] + b3_0) * h0);
                atomicAdd(agg + dofs + c0 + 16, (acc[mt][1][r] + b3_1) * h1);
            }
    }
}

// ================= node output =================
__global__ __launch_bounds__(256, 3)
void k_nodeout(const unsigned short* __restrict__ AH,
               const float* __restrict__ agg,
               const unsigned short* __restrict__ Wb,
               const float* __restrict__ bpd, const float* __restrict__ bpu,
               const float* __restrict__ bt1, const float* __restrict__ bt2,
               float* __restrict__ out) {
    __shared__ unsigned short Xh[64 * 136];
    __shared__ unsigned short Xa[64 * 136];
    int tid = threadIdx.x, lane = tid & 63, wv = tid >> 6;
    int n0 = blockIdx.x * 64;
    {
        int row = tid >> 2, q = tid & 3;
        int n = n0 + row;
        if (n < NN) {
            const u16x8* hp = (const u16x8*)(AH + (size_t)n * 256 + 128 + q * 32);
#pragma unroll
            for (int i = 0; i < 4; ++i)
                *(u16x8*)(Xh + row * 136 + q * 32 + i * 8) = hp[i];
            stage_f32row(Xa + row * 136 + q * 32,
                         (const f32x4*)(agg + (size_t)n * 128 + q * 32));
        } else {
            u16x8 z = {0, 0, 0, 0, 0, 0, 0, 0};
#pragma unroll
            for (int i = 0; i < 4; ++i) {
                *(u16x8*)(Xh + row * 136 + q * 32 + i * 8) = z;
                *(u16x8*)(Xa + row * 136 + q * 32 + i * 8) = z;
            }
        }
    }
    __syncthreads();
    bf16x8 wfa[4][2], wfb[4][2];
    load_wfrags(Wb + 5 * 16384, wv, lane, wfa);   // Wpd
    load_wfrags(Wb + 6 * 16384, wv, lane, wfb);   // Wpu
    int c0 = 32 * wv + (lane & 15);
    int rbase = (lane >> 4) * 4;
    f32x4 acc[4][2];
    zero_acc(acc);
    gemm64(Xh, wfa, acc, lane);
    gemm64(Xa, wfb, acc, lane);
    float bb0 = bpd[c0] + bpu[c0], bb1 = bpd[c0 + 16] + bpu[c0 + 16];
    __syncthreads();
    epi_lds(Xh, acc, bb0, bb1, c0, rbase);
    __syncthreads();
    load_wfrags(Wb + 7 * 16384, wv, lane, wfa);   // Wth1
    zero_acc(acc);
    gemm64(Xh, wfa, acc, lane);
    float b10 = bt1[c0], b11 = bt1[c0 + 16];
    __syncthreads();
    epi_lds(Xa, acc, b10, b11, c0, rbase);
    __syncthreads();
    load_wfrags(Wb + 8 * 16384, wv, lane, wfb);   // Wth2
    zero_acc(acc);
    gemm64(Xa, wfb, acc, lane);
    float b20 = bt2[c0], b21 = bt2[c0 + 16];
#pragma unroll
    for (int mt = 0; mt < 4; ++mt)
#pragma unroll
        for (int r = 0; r < 4; ++r) {
            int n = n0 + mt * 16 + rbase + r;
            if (n < NN) {
                out[(size_t)n * 128 + c0]      = acc[mt][0][r] + b20;
                out[(size_t)n * 128 + c0 + 16] = acc[mt][1][r] + b21;
            }
        }
}

extern "C" void kernel_launch(void* const* d_in, const int* in_sizes, int n_in,
                              void* d_out, int out_size, void* d_ws, size_t ws_size,
                              hipStream_t stream) {
    (void)in_sizes; (void)n_in; (void)out_size;
    const float* node_feat = (const float*)d_in[0];
    const float* edge_feat = (const float*)d_in[1];
    const int*   src  = (const int*)d_in[2];
    const int*   dst  = (const int*)d_in[3];
    const float* Wsrc = (const float*)d_in[4];  const float* bsrc = (const float*)d_in[5];
    const float* Wdst = (const float*)d_in[6];  const float* bdst = (const float*)d_in[7];
    const float* Wphi1 = (const float*)d_in[8]; const float* bphi1 = (const float*)d_in[9];
    const float* Wphi2 = (const float*)d_in[10];const float* bphi2 = (const float*)d_in[11];
    const float* Wphi3 = (const float*)d_in[12];const float* bphi3 = (const float*)d_in[13];
    const float* Wth1 = (const float*)d_in[14]; const float* bth1 = (const float*)d_in[15];
    const float* Wth2 = (const float*)d_in[16]; const float* bth2 = (const float*)d_in[17];
    const float* Wpd  = (const float*)d_in[18]; const float* bpd  = (const float*)d_in[19];
    const float* Wpu  = (const float*)d_in[20]; const float* bpu  = (const float*)d_in[21];

    // workspace carve (~272.6 MB primary)
    char* ws = (char*)d_ws;
    size_t off = 0;
    unsigned short* Wb   = (unsigned short*)(ws + off); off += 294912;
    unsigned short* AH   = (unsigned short*)(ws + off); off += 25600000;   // [Asrc|Hb]
    unsigned short* Adst = (unsigned short*)(ws + off); off += 12800000;
    float*          agg  = (float*)(ws + off);          off += 25600000;
    int*            cnt  = (int*)(ws + off);            off += 200064;
    int*            rowptr = (int*)(ws + off);          off += 200064;
    int*            bsum = (int*)(ws + off);            off += 1024;
    int*            pos  = (int*)(ws + off);            off += 3200000;
    unsigned short* Mbuf = (unsigned short*)(ws + off); off += 204800000;
    bool primary = (ws_size >= off);

    k_wconv<<<36, 256, 0, stream>>>(Wsrc, Wdst, Wphi1, Wphi2, Wphi3,
                                    Wpd, Wpu, Wth1, Wth2, Wb);
    k_nodepre<<<782, 256, 0, stream>>>(node_feat, Wb, bsrc, bdst, AH, Adst);

    if (primary) {
        hipMemsetAsync(cnt, 0, (size_t)NN * 4, stream);
        k_hist<<<3125, 256, 0, stream>>>(dst, cnt);
        k_scan1<<<NBLK_SCAN, 256, 0, stream>>>(cnt, bsum);
        k_scan2<<<1, 256, 0, stream>>>(bsum);
        k_scan3<<<NBLK_SCAN, 256, 0, stream>>>(cnt, bsum, rowptr);
        k_pos<<<3125, 256, 0, stream>>>(dst, cnt, pos);
        k_edgeB<<<GRID_E, 256, 0, stream>>>(edge_feat, src, dst, pos,
                                            AH, Adst, Wb,
                                            bphi1, bphi2, bphi3, Mbuf);
        k_agg<<<12500, 256, 0, stream>>>(Mbuf, rowptr, agg);
    } else {
        hipMemsetAsync(agg, 0, (size_t)NN * 128 * 4, stream);
        k_edge_atomic<<<1024, 256, 0, stream>>>(edge_feat, src, dst,
                                                AH, Adst, Wb,
                                                bphi1, bphi2, bphi3, agg);
    }
    k_nodeout<<<782, 256, 0, stream>>>(AH, agg, Wb, bpd, bpu, bth1, bth2,
                                       (float*)d_out);
}